// Round 26
// baseline (125.646 us; speedup 1.0000x reference)
//
#include <hip/hip_runtime.h>
#include <hip/hip_bf16.h>

typedef __attribute__((ext_vector_type(8))) short bf16x8;
typedef __attribute__((ext_vector_type(4))) float f32x4;
typedef unsigned short u16;

#define MFMA16(a, b, c) __builtin_amdgcn_mfma_f32_16x16x32_bf16(a, b, c, 0, 0, 0)
#define GLL(srcp, dstp) __builtin_amdgcn_global_load_lds(                      \
    (const __attribute__((address_space(1))) void*)(srcp),                     \
    (__attribute__((address_space(3))) void*)(dstp), 16, 0, 0)

__device__ __forceinline__ u16 f2b(float f) {
  union { float f; unsigned u; } a; a.f = f;
  return (u16)((a.u + 0x7FFFu + ((a.u >> 16) & 1u)) >> 16);
}
// paired f32->bf16 (compiler emits v_cvt_pk_bf16_f32; RTNE, same as f2b)
__device__ __forceinline__ unsigned pk2(float lo, float hi) {
  __hip_bfloat162 h = __float22bfloat162_rn(make_float2(lo, hi));
  return *reinterpret_cast<unsigned*>(&h);
}

// ---------------- fused prep ----------------
// blocks [0,3584): x f32->bf16 + k_cache f32->bf16 row-remap (917504 chunks of 4)
// blocks [3584,3968): old-V transpose tiles (vc -> vT2 cols 0..1535, slot-permuted)
__global__ __launch_bounds__(256) void prep(const float* __restrict__ x,
                                            const float* __restrict__ kc,
                                            const float* __restrict__ vc,
                                            u16* __restrict__ xb,
                                            u16* __restrict__ kfull,
                                            u16* __restrict__ vT) {
  __shared__ float tile[64][65];
  const int blk = blockIdx.x;
  const int t = threadIdx.x;
  if (blk < 3584) {
    const int c = blk * 256 + t;  // 917504 chunks of 4
    const float* src;
    u16* dst;
    if (c < 524288) {
      src = x + (size_t)c * 4; dst = xb + (size_t)c * 4;
    } else {
      int l = c - 524288;
      int bh = l / 24576, r = l - bh * 24576;
      src = kc + (size_t)bh * 98304 + (size_t)r * 4;
      dst = kfull + (size_t)bh * 131072 + (size_t)r * 4;
    }
    const float4 v = *(const float4*)src;
    ushort4 o;
    o.x = f2b(v.x); o.y = f2b(v.y); o.z = f2b(v.z); o.w = f2b(v.w);
    *(ushort4*)dst = o;
    return;
  }
  // old-V transpose: vb in [0,384) -> kt in [0,24), bh in [0,16)
  const int vb = blk - 3584;
  const int kt = vb % 24, bh = vb / 24;
  const float* src = vc + ((size_t)bh * 1536 + (size_t)kt * 64) * 64;
  const int colbase = kt * 64;
#pragma unroll
  for (int j = 0; j < 4; j++) {
    int e = t + j * 256;            // 0..1023 chunks of 4
    int r = e >> 4, c = (e & 15) * 4;
    float4 v = *(const float4*)(src + (size_t)r * 64 + c);
    tile[r][c] = v.x; tile[r][c + 1] = v.y; tile[r][c + 2] = v.z; tile[r][c + 3] = v.w;
  }
  __syncthreads();
  int d = t >> 2, kv0 = (t & 3) * 16;
  // slot permutation: local kv l = kv0+i has cc=i, jb=kv0>>4 -> slot i*4 + (kv0>>4)
  u16* dst = vT + ((size_t)bh * 64 + d) * 2048 + colbase + (kv0 >> 4);
#pragma unroll
  for (int i = 0; i < 16; i++) dst[i * 4] = f2b(tile[kv0 + i][d]);
}

// new-V transpose -> vT2 cols 1536..2047 (slot-permuted), reads newv (after postproc)
__global__ __launch_bounds__(256) void vtrn(const float* __restrict__ newv,
                                            u16* __restrict__ vT) {
  __shared__ float tile[64][65];
  const int ktp = blockIdx.x, bh = blockIdx.y;  // ktp in [0,8)
  const float* src = newv + ((size_t)bh * 512 + (size_t)ktp * 64) * 64;
  const int colbase = 1536 + ktp * 64;
  const int t = threadIdx.x;
#pragma unroll
  for (int j = 0; j < 4; j++) {
    int e = t + j * 256;
    int r = e >> 4, c = (e & 15) * 4;
    float4 v = *(const float4*)(src + (size_t)r * 64 + c);
    tile[r][c] = v.x; tile[r][c + 1] = v.y; tile[r][c + 2] = v.z; tile[r][c + 3] = v.w;
  }
  __syncthreads();
  int d = t >> 2, kv0 = (t & 3) * 16;
  u16* dst = vT + ((size_t)bh * 64 + d) * 2048 + colbase + (kv0 >> 4);
#pragma unroll
  for (int i = 0; i < 16; i++) dst[i * 4] = f2b(tile[kv0 + i][d]);
}

// zero-init out region (required per call: harness does not re-poison between replays)
__global__ __launch_bounds__(256) void zero4(float* __restrict__ p) {
  *(float4*)(p + (size_t)(blockIdx.x * 256 + threadIdx.x) * 4) =
      make_float4(0.f, 0.f, 0.f, 0.f);
}

// ---------------- GEMM: K-split 2; partial write OR atomic merge ----------------
// 64x128 tile, BK=64, XCD col-tile colocation.
// A bf16 (GLL, dbuf LDS, counted vmcnt). B fp32 direct, depth-2 reg-staging.
// atomicOut=0: Cp[ks][M][N] partials. atomicOut=1: atomicAdd into Cp[M][N] (zeroed).
__global__ __launch_bounds__(256, 3) void gemm_bt(const u16* __restrict__ A,
                                                  const float* __restrict__ B0,
                                                  const float* __restrict__ B1,
                                                  const float* __restrict__ B2,
                                                  float* __restrict__ Cp,
                                                  int M, int N, int K, int nb1, int nb2,
                                                  int atomicOut) {
  __shared__ __attribute__((aligned(16))) u16 As[2][4096];  // [buf][64 rows][64]
  __shared__ __attribute__((aligned(16))) u16 Bs[2][8192];  // [buf][128 rows][64]
  const int t = threadIdx.x;
  const int lane = t & 63, w = t >> 6;
  const int wr = (w >> 1) * 32, wc = (w & 1) * 64;
  const int g = lane >> 4, cc = lane & 15;
  const int nby = N >> 7, cpx = nby >> 3, nrt = M >> 6;
  const int j = blockIdx.x & 7, q = blockIdx.x >> 3;
  const int ct = j * cpx + (q % cpx);
  const int rest = q / cpx;
  const int rt = rest % nrt, ks = rest / nrt;
  const size_t row0 = (size_t)rt * 64;
  const int col0 = ct * 128;
  const int k0base = ks * (K >> 1);

  const int lr = lane >> 3, lc = lane & 7;
  const int swz = lc ^ lr;
  const u16* aS = A + (row0 + w * 16 + lr) * (size_t)K + swz * 8 + k0base;
  const float* Bb;
  int brow;
  if (col0 < nb1) { Bb = B0; brow = col0; }
  else if (col0 < nb2) { Bb = B1; brow = col0 - nb1; }
  else { Bb = B2; brow = col0 - nb2; }
  const float* bS = Bb + (brow + w * 32 + lr) * (size_t)K + swz * 8 + k0base;

  f32x4 acc[2][4] = {};
  f32x4 blA[4][2], blB[4][2];

#define ALOAD(bufi, kk0)                                                       \
  {                                                                            \
    _Pragma("unroll") for (int i = 0; i < 2; i++)                              \
        GLL(aS + (size_t)(i * 8) * K + (kk0), &As[bufi][(w * 16 + i * 8) * 64]); \
  }
#define BLOAD(blv, kk0)                                                        \
  {                                                                            \
    _Pragma("unroll") for (int i = 0; i < 4; i++) {                            \
      blv[i][0] = *(const f32x4*)(bS + (size_t)(i * 8) * K + (kk0));           \
      blv[i][1] = *(const f32x4*)(bS + (size_t)(i * 8) * K + (kk0) + 4);       \
    }                                                                          \
  }
#define BWRITE(blv, bufi)                                                      \
  {                                                                            \
    _Pragma("unroll") for (int i = 0; i < 4; i++) {                            \
      uint4 pw;                                                                \
      pw.x = pk2(blv[i][0][0], blv[i][0][1]);                                  \
      pw.y = pk2(blv[i][0][2], blv[i][0][3]);                                  \
      pw.z = pk2(blv[i][1][0], blv[i][1][1]);                                  \
      pw.w = pk2(blv[i][1][2], blv[i][1][3]);                                  \
      *(uint4*)&Bs[bufi][(w * 32 + i * 8 + lr) * 64 + lc * 8] = pw;            \
    }                                                                          \
  }

  const int niter = (K >> 1) >> 6;  // 16

  ALOAD(0, 0);
  BLOAD(blA, 0);
  BWRITE(blA, 0);
  BLOAD(blB, 64);
  asm volatile("s_waitcnt lgkmcnt(0)" ::: "memory");
  __builtin_amdgcn_s_barrier();

#define GBODY(it_, blPrev, blCur)                                              \
  {                                                                            \
    const int buf = (it_) & 1;                                                 \
    if ((it_) > 0) {                                                           \
      if ((it_) + 1 < niter) {                                                 \
        asm volatile("s_waitcnt vmcnt(8)" ::: "memory");                       \
      } else {                                                                 \
        asm volatile("s_waitcnt vmcnt(0)" ::: "memory");                       \
      }                                                                        \
      asm volatile("s_waitcnt lgkmcnt(0)" ::: "memory");                       \
      __builtin_amdgcn_s_barrier();                                            \
    }                                                                          \
    if ((it_) + 1 < niter) ALOAD(buf ^ 1, ((it_) + 1) * 64);                   \
    if ((it_) + 2 < niter) BLOAD(blCur, ((it_) + 2) * 64);                     \
    bf16x8 av[2][2], bv[4][2];                                                 \
    _Pragma("unroll") for (int m = 0; m < 2; m++) {                            \
      const int row = wr + m * 16 + cc;                                        \
      _Pragma("unroll") for (int kk = 0; kk < 2; kk++)                         \
          av[m][kk] =                                                          \
              *(const bf16x8*)(&As[buf][row * 64 + (((kk * 4 + g) ^ (cc & 7)) * 8)]); \
    }                                                                          \
    _Pragma("unroll") for (int n = 0; n < 4; n++) {                            \
      const int row = wc + n * 16 + cc;                                        \
      _Pragma("unroll") for (int kk = 0; kk < 2; kk++)                         \
          bv[n][kk] =                                                          \
              *(const bf16x8*)(&Bs[buf][row * 64 + (((kk * 4 + g) ^ (cc & 7)) * 8)]); \
    }                                                                          \
    _Pragma("unroll") for (int kk = 0; kk < 2; kk++)                           \
        _Pragma("unroll") for (int m = 0; m < 2; m++)                          \
        _Pragma("unroll") for (int n = 0; n < 4; n++)                          \
            acc[m][n] = MFMA16(av[m][kk], bv[n][kk], acc[m][n]);               \
    if ((it_) + 1 < niter) BWRITE(blPrev, buf ^ 1);                            \
  }

  for (int it = 0; it < niter; it += 2) {
    GBODY(it, blB, blA);
    GBODY(it + 1, blA, blB);
  }
#undef GBODY
#undef ALOAD
#undef BLOAD
#undef BWRITE

  if (atomicOut) {
    // 2-way atomic merge: exactly two adds per element from 0 -> fl(a+b), order-invariant
#pragma unroll
    for (int m = 0; m < 2; m++)
#pragma unroll
      for (int n = 0; n < 4; n++)
#pragma unroll
        for (int r = 0; r < 4; r++)
          atomicAdd(&Cp[(row0 + wr + m * 16 + g * 4 + r) * N + (col0 + wc + n * 16 + cc)],
                    acc[m][n][r]);
  } else {
    float* Cw = Cp + (size_t)ks * M * N;
#pragma unroll
    for (int m = 0; m < 2; m++)
#pragma unroll
      for (int n = 0; n < 4; n++)
#pragma unroll
        for (int r = 0; r < 4; r++)
          Cw[(row0 + wr + m * 16 + g * 4 + r) * N + (col0 + wc + n * 16 + cc)] = acc[m][n][r];
  }
}

// ---------------- RoPE + scatter (reads K-split partial sums) ----------------
__global__ __launch_bounds__(256) void postproc(const float* __restrict__ Cp0,
                                                const float* __restrict__ Cp1,
                                                const float* __restrict__ fcos,
                                                const float* __restrict__ fsin,
                                                u16* __restrict__ qrope,
                                                u16* __restrict__ kfull,
                                                float* __restrict__ newk,
                                                float* __restrict__ newv) {
  int idx = blockIdx.x * 256 + threadIdx.x;
  if (idx >= 1024 * 1536) return;
  int m = idx / 1536, p = idx - m * 1536;
  int b = m >> 9, s = m & 511;
  const float* r0 = Cp0 + (size_t)m * 3072;
  const float* r1 = Cp1 + (size_t)m * 3072;
  if (p < 1280) {
    bool isq = p < 1024;
    int pk = isq ? p : p - 1024;
    int h = pk >> 5, i = pk & 31;
    int colbase = (isq ? 0 : 2048) + h * 64 + 2 * i;
    float xr = r0[colbase] + r1[colbase];
    float xi = r0[colbase + 1] + r1[colbase + 1];
    float co = fcos[s * 32 + i], si = fsin[s * 32 + i];
    float orr = xr * co - xi * si;
    float oii = xr * si + xi * co;
    if (isq) {
      u16* dst = qrope + (((size_t)(b * 32 + h) * 512 + s) * 64 + 2 * i);
      dst[0] = f2b(orr); dst[1] = f2b(oii);
    } else {
      size_t o0 = ((size_t)(b * 8 + h) * 512 + s) * 64 + 2 * i;
      newk[o0] = orr; newk[o0 + 1] = oii;
      u16* kf = kfull + (((size_t)(b * 8 + h) * 2048 + 1536 + s) * 64 + 2 * i);
      kf[0] = f2b(orr); kf[1] = f2b(oii);
    }
  } else {
    int pv = p - 1280;
    int h = pv >> 5, i = pv & 31;
    int cb = 2560 + h * 64 + 2 * i;
    float v0 = r0[cb] + r1[cb], v1 = r0[cb + 1] + r1[cb + 1];
    size_t o0 = ((size_t)(b * 8 + h) * 512 + s) * 64 + 2 * i;
    newv[o0] = v0; newv[o0 + 1] = v1;
  }
}

// ---------------- flash attention: 8-wave blocks, KV-split 2-way ----------------
// 4-deep LDS pipeline, raw s_barrier + counted vmcnt (T3/T4), setprio on MFMA (T5).
// Packed-b64 P writes (kv-slot permutation matching vT2).
__global__ __launch_bounds__(512, 4) void attn_split(const u16* __restrict__ qrope,
                                                     const u16* __restrict__ kfull,
                                                     const u16* __restrict__ vT,
                                                     const float* __restrict__ mask,
                                                     float* __restrict__ po,
                                                     float* __restrict__ ml) {
  __shared__ __attribute__((aligned(16))) u16 Ks[4][4096];  // [buf][64 kv][64 d] 32KB
  __shared__ __attribute__((aligned(16))) u16 Vs[4][4096];  // [buf][64 d][64 kv] 32KB
  __shared__ __attribute__((aligned(16))) u16 P_lds[8192];  // 8 waves x 16x64   16KB
  const int t = threadIdx.x, lane = t & 63, w = t >> 6;  // w in 0..7
  const int g = lane >> 4, cc = lane & 15;
  const int p = blockIdx.x;
  const int v = (p & 7) * 64 + (p >> 3);
  const int bh = v >> 3, qt = (v >> 1) & 3, sp = v & 1;
  const int b = bh >> 5, h = bh & 31;
  const int bhkv = b * 8 + (h >> 2);
  const int s0 = qt * 128 + w * 16;
  const int j0beg = sp * 1024;

  const int lr = lane >> 3, lc = lane & 7;
  const int swzc = lc ^ lr;

  bf16x8 qa0, qa1;
  {
    const u16* qb = qrope + ((size_t)bh * 512 + s0 + cc) * 64 + g * 8;
    qa0 = *(const bf16x8*)qb;
    qa1 = *(const bf16x8*)(qb + 32);
  }
  float mrow[4], lsum[4];
  f32x4 o[4] = {};
#pragma unroll
  for (int r = 0; r < 4; r++) { mrow[r] = -1e30f; lsum[r] = 0.0f; }

  u16* Pw = P_lds + w * 1024;
  const float* mbase = mask + (size_t)(s0 + g * 4) * 2048 + cc;
  const u16* ksrc0 = kfull + (size_t)bhkv * 131072 + (size_t)(w * 8 + lr) * 64 + swzc * 8;
  const u16* vsrc0 = vT + ((size_t)bhkv * 64 + w * 8 + lr) * 2048 + swzc * 8;

#pragma unroll
  for (int pt = 0; pt < 3; ++pt) {
    GLL(ksrc0 + (size_t)(j0beg + pt * 64) * 64, &Ks[pt][w * 512]);
    GLL(vsrc0 + (j0beg + pt * 64), &Vs[pt][w * 512]);
  }

  for (int it = 0; it < 16; ++it) {
    const int buf = it & 3;
    const int j0 = j0beg + it * 64;
    if (it < 14) {
      asm volatile("s_waitcnt vmcnt(4)" ::: "memory");
    } else if (it == 14) {
      asm volatile("s_waitcnt vmcnt(2)" ::: "memory");
    } else {
      asm volatile("s_waitcnt vmcnt(0)" ::: "memory");
    }
    __builtin_amdgcn_s_barrier();

    float mk[4][4];
#pragma unroll
    for (int r = 0; r < 4; r++)
#pragma unroll
      for (int jb = 0; jb < 4; jb++)
        mk[r][jb] = mbase[(size_t)r * 2048 + j0 + jb * 16];
    __builtin_amdgcn_sched_barrier(0);
    if (it < 13) {
      GLL(ksrc0 + (size_t)(j0 + 192) * 64, &Ks[(it + 3) & 3][w * 512]);
      GLL(vsrc0 + (j0 + 192), &Vs[(it + 3) & 3][w * 512]);
    }

    f32x4 sc[4];
    __builtin_amdgcn_s_setprio(1);
#pragma unroll
    for (int jb = 0; jb < 4; jb++) {
      const bf16x8 k0 = *(const bf16x8*)(&Ks[buf][(jb * 16 + cc) * 64 + ((g ^ (cc & 7)) * 8)]);
      const bf16x8 k1 =
          *(const bf16x8*)(&Ks[buf][(jb * 16 + cc) * 64 + (((g + 4) ^ (cc & 7)) * 8)]);
      f32x4 z = {0.f, 0.f, 0.f, 0.f};
      z = MFMA16(qa0, k0, z);
      z = MFMA16(qa1, k1, z);
      sc[jb] = z;
    }
    __builtin_amdgcn_s_setprio(0);
    float pp[4][4];
#pragma unroll
    for (int r = 0; r < 4; r++) {
#pragma unroll
      for (int jb = 0; jb < 4; jb++)
        pp[r][jb] = sc[jb][r] * 0.125f + mk[r][jb];
      const float lm = fmaxf(fmaxf(pp[r][0], pp[r][1]), fmaxf(pp[r][2], pp[r][3]));
      if (__any(lm > mrow[r] + 8.0f)) {
        float tm = lm;
#pragma unroll
        for (int off = 1; off < 16; off <<= 1) tm = fmaxf(tm, __shfl_xor(tm, off, 64));
        const float newm = fmaxf(mrow[r], tm);
        const float corr = __expf(mrow[r] - newm);
        mrow[r] = newm;
        lsum[r] *= corr;
#pragma unroll
        for (int db = 0; db < 4; db++) o[db][r] *= corr;
      }
      float ps = 0.f;
#pragma unroll
      for (int jb = 0; jb < 4; jb++) { pp[r][jb] = __expf(pp[r][jb] - mrow[r]); ps += pp[r][jb]; }
      lsum[r] += ps;
      // packed P write: value(kv=jb*16+cc) -> slot cc*4+jb; bytes cc*8+jb*2, XOR sw
      const int rowb = (g * 4 + r) * 128;
      const int sw = ((g * 4 + r) & 7) << 4;
      uint2 pw;
      pw.x = pk2(pp[r][0], pp[r][1]);
      pw.y = pk2(pp[r][2], pp[r][3]);
      *(uint2*)((char*)Pw + ((rowb + cc * 8) ^ sw)) = pw;
    }
    __builtin_amdgcn_s_setprio(1);
#pragma unroll
    for (int kk = 0; kk < 2; kk++) {
      const bf16x8 pa =
          *(const bf16x8*)(Pw + (((cc * 128 + kk * 64 + g * 16) ^ ((cc & 7) << 4)) >> 1));
#pragma unroll
      for (int db = 0; db < 4; db++) {
        const bf16x8 vf =
            *(const bf16x8*)(&Vs[buf][(db * 16 + cc) * 64 + (((kk * 4 + g) ^ (cc & 7)) * 8)]);
        o[db] = MFMA16(pa, vf, o[db]);
      }
    }
    __builtin_amdgcn_s_setprio(0);
  }
#pragma unroll
  for (int r = 0; r < 4; r++) {
    float ps = lsum[r];
#pragma unroll
    for (int off = 1; off < 16; off <<= 1) ps += __shfl_xor(ps, off, 64);
    const size_t row = (size_t)bh * 512 + s0 + g * 4 + r;
    float* dst = po + (row * 2 + sp) * 64 + cc;
#pragma unroll
    for (int db = 0; db < 4; db++) dst[db * 16] = o[db][r];
    if (cc == 0) {
      float2* mlp = (float2*)ml;
      mlp[row * 2 + sp] = make_float2(mrow[r], ps);
    }
  }
}

// combine 2 splits -> aout bf16 [1024][2048] (b,s, h*64+d)
__global__ __launch_bounds__(256) void attn_combine(const float* __restrict__ po,
                                                    const float* __restrict__ ml,
                                                    u16* __restrict__ aout) {
  const int t = threadIdx.x;
  const int row = blockIdx.x * 4 + (t >> 6);  // bh*512 + s
  const int d = t & 63;
  const int bh = row >> 9, s = row & 511;
  const int b = bh >> 5, h = bh & 31;
  const float2* mlp = (const float2*)ml;
  const float2 m0 = mlp[row * 2 + 0], m1 = mlp[row * 2 + 1];
  const float M = fmaxf(m0.x, m1.x);
  const float w0 = __expf(m0.x - M), w1 = __expf(m1.x - M);
  const float L = m0.y * w0 + m1.y * w1;
  const float o = po[(size_t)(row * 2 + 0) * 64 + d] * w0 +
                  po[(size_t)(row * 2 + 1) * 64 + d] * w1;
  aout[((size_t)(b * 512 + s)) * 2048 + h * 64 + d] = f2b(o / L);
}

// ---------------- launch ----------------
extern "C" void kernel_launch(void* const* d_in, const int* in_sizes, int n_in,
                              void* d_out, int out_size, void* d_ws, size_t ws_size,
                              hipStream_t stream) {
  (void)in_sizes; (void)n_in; (void)out_size; (void)ws_size;
  const float* x    = (const float*)d_in[0];
  const float* fcos = (const float*)d_in[1];
  const float* fsin = (const float*)d_in[2];
  const float* kc   = (const float*)d_in[3];
  const float* vc   = (const float*)d_in[4];
  const float* mask = (const float*)d_in[5];
  const float* wq   = (const float*)d_in[6];
  const float* wk   = (const float*)d_in[7];
  const float* wv   = (const float*)d_in[8];
  const float* wo   = (const float*)d_in[9];

  float* out_f = (float*)d_out;                 // [2][512][2048]
  float* newk  = out_f + 2097152;               // [2][8][512][64]
  float* newv  = out_f + 2621440;               // [2][8][512][64]

  u16*   xb    = (u16*)d_ws;                    // 4MB   @0    (dead after gemm1)
  float* Cp    = (float*)(xb + 2097152);        // 24MB  @4MB  (2 partials; dead after postproc)
  float* Cp1   = Cp + 3145728;
  u16*   qrope = (u16*)(Cp + 6291456);          // 4MB   @28MB
  u16*   kfull = qrope + 2097152;               // 4MB   @32MB
  u16*   vTf   = kfull + 2097152;               // 4MB   @36MB
  u16*   aout  = vTf + 2097152;                 // 4MB   @40MB
  float* ml    = (float*)(aout + 2097152);      // 0.5MB @44MB
  // phase aliases:
  float* po    = (float*)d_ws;                  // 16MB @0 (over xb+Cp0; both dead by attn)

  prep<<<3968, 256, 0, stream>>>(x, kc, vc, xb, kfull, vTf);

  gemm_bt<<<768, 256, 0, stream>>>(xb, wq, wk, wv, Cp,
                                   1024, 3072, 2048, 2048, 2560, 0);
  postproc<<<6144, 256, 0, stream>>>(Cp, Cp1, fcos, fsin, qrope, kfull, newk, newv);
  vtrn<<<dim3(8, 16), 256, 0, stream>>>(newv, vTf);
  attn_split<<<512, 512, 0, stream>>>(qrope, kfull, vTf, mask, po, ml);
  attn_combine<<<8192, 256, 0, stream>>>(po, ml, aout);
  zero4<<<2048, 256, 0, stream>>>(out_f);
  gemm_bt<<<512, 256, 0, stream>>>(aout, wo, wo, wo, out_f,
                                   1024, 2048, 2048, 4096, 8192, 1);
}

// Round 27
// 120.181 us; speedup vs baseline: 1.0455x; 1.0455x over previous
//
#include <hip/hip_runtime.h>
#include <hip/hip_bf16.h>

typedef __attribute__((ext_vector_type(8))) short bf16x8;
typedef __attribute__((ext_vector_type(4))) float f32x4;
typedef unsigned short u16;

#define MFMA16(a, b, c) __builtin_amdgcn_mfma_f32_16x16x32_bf16(a, b, c, 0, 0, 0)
#define GLL(srcp, dstp) __builtin_amdgcn_global_load_lds(                      \
    (const __attribute__((address_space(1))) void*)(srcp),                     \
    (__attribute__((address_space(3))) void*)(dstp), 16, 0, 0)

__device__ __forceinline__ u16 f2b(float f) {
  union { float f; unsigned u; } a; a.f = f;
  return (u16)((a.u + 0x7FFFu + ((a.u >> 16) & 1u)) >> 16);
}
// paired f32->bf16 (compiler emits v_cvt_pk_bf16_f32; RTNE, same as f2b)
__device__ __forceinline__ unsigned pk2(float lo, float hi) {
  __hip_bfloat162 h = __float22bfloat162_rn(make_float2(lo, hi));
  return *reinterpret_cast<unsigned*>(&h);
}

// ---------------- fused prep ----------------
// blocks [0,3584): x f32->bf16 + k_cache f32->bf16 row-remap (917504 chunks of 4)
// blocks [3584,3968): old-V transpose tiles (vc -> vT2 cols 0..1535, slot-permuted)
__global__ __launch_bounds__(256) void prep(const float* __restrict__ x,
                                            const float* __restrict__ kc,
                                            const float* __restrict__ vc,
                                            u16* __restrict__ xb,
                                            u16* __restrict__ kfull,
                                            u16* __restrict__ vT) {
  __shared__ float tile[64][65];
  const int blk = blockIdx.x;
  const int t = threadIdx.x;
  if (blk < 3584) {
    const int c = blk * 256 + t;  // 917504 chunks of 4
    const float* src;
    u16* dst;
    if (c < 524288) {
      src = x + (size_t)c * 4; dst = xb + (size_t)c * 4;
    } else {
      int l = c - 524288;
      int bh = l / 24576, r = l - bh * 24576;
      src = kc + (size_t)bh * 98304 + (size_t)r * 4;
      dst = kfull + (size_t)bh * 131072 + (size_t)r * 4;
    }
    const float4 v = *(const float4*)src;
    ushort4 o;
    o.x = f2b(v.x); o.y = f2b(v.y); o.z = f2b(v.z); o.w = f2b(v.w);
    *(ushort4*)dst = o;
    return;
  }
  // old-V transpose: vb in [0,384) -> kt in [0,24), bh in [0,16)
  const int vb = blk - 3584;
  const int kt = vb % 24, bh = vb / 24;
  const float* src = vc + ((size_t)bh * 1536 + (size_t)kt * 64) * 64;
  const int colbase = kt * 64;
#pragma unroll
  for (int j = 0; j < 4; j++) {
    int e = t + j * 256;            // 0..1023 chunks of 4
    int r = e >> 4, c = (e & 15) * 4;
    float4 v = *(const float4*)(src + (size_t)r * 64 + c);
    tile[r][c] = v.x; tile[r][c + 1] = v.y; tile[r][c + 2] = v.z; tile[r][c + 3] = v.w;
  }
  __syncthreads();
  int d = t >> 2, kv0 = (t & 3) * 16;
  // slot permutation: local kv l = kv0+i has cc=i, jb=kv0>>4 -> slot i*4 + (kv0>>4)
  u16* dst = vT + ((size_t)bh * 64 + d) * 2048 + colbase + (kv0 >> 4);
#pragma unroll
  for (int i = 0; i < 16; i++) dst[i * 4] = f2b(tile[kv0 + i][d]);
}

// new-V transpose -> vT2 cols 1536..2047 (slot-permuted), reads newv (after postproc)
__global__ __launch_bounds__(256) void vtrn(const float* __restrict__ newv,
                                            u16* __restrict__ vT) {
  __shared__ float tile[64][65];
  const int ktp = blockIdx.x, bh = blockIdx.y;  // ktp in [0,8)
  const float* src = newv + ((size_t)bh * 512 + (size_t)ktp * 64) * 64;
  const int colbase = 1536 + ktp * 64;
  const int t = threadIdx.x;
#pragma unroll
  for (int j = 0; j < 4; j++) {
    int e = t + j * 256;
    int r = e >> 4, c = (e & 15) * 4;
    float4 v = *(const float4*)(src + (size_t)r * 64 + c);
    tile[r][c] = v.x; tile[r][c + 1] = v.y; tile[r][c + 2] = v.z; tile[r][c + 3] = v.w;
  }
  __syncthreads();
  int d = t >> 2, kv0 = (t & 3) * 16;
  u16* dst = vT + ((size_t)bh * 64 + d) * 2048 + colbase + (kv0 >> 4);
#pragma unroll
  for (int i = 0; i < 16; i++) dst[i * 4] = f2b(tile[kv0 + i][d]);
}

// ---------------- GEMM: Cp[ks][M][N] partial = A[M][Khalf] * B[N][Khalf]^T ----------------
// 64x128 tile, K-split 2, BK=64, XCD col-tile colocation.
// A bf16 (GLL, dbuf LDS, counted vmcnt). B fp32 direct, depth-2 reg-staging.
__global__ __launch_bounds__(256, 3) void gemm_bt(const u16* __restrict__ A,
                                                  const float* __restrict__ B0,
                                                  const float* __restrict__ B1,
                                                  const float* __restrict__ B2,
                                                  float* __restrict__ Cp,
                                                  int M, int N, int K, int nb1, int nb2) {
  __shared__ __attribute__((aligned(16))) u16 As[2][4096];  // [buf][64 rows][64]
  __shared__ __attribute__((aligned(16))) u16 Bs[2][8192];  // [buf][128 rows][64]
  const int t = threadIdx.x;
  const int lane = t & 63, w = t >> 6;
  const int wr = (w >> 1) * 32, wc = (w & 1) * 64;
  const int g = lane >> 4, cc = lane & 15;
  const int nby = N >> 7, cpx = nby >> 3, nrt = M >> 6;
  const int j = blockIdx.x & 7, q = blockIdx.x >> 3;
  const int ct = j * cpx + (q % cpx);
  const int rest = q / cpx;
  const int rt = rest % nrt, ks = rest / nrt;
  const size_t row0 = (size_t)rt * 64;
  const int col0 = ct * 128;
  const int k0base = ks * (K >> 1);

  const int lr = lane >> 3, lc = lane & 7;
  const int swz = lc ^ lr;
  const u16* aS = A + (row0 + w * 16 + lr) * (size_t)K + swz * 8 + k0base;
  const float* Bb;
  int brow;
  if (col0 < nb1) { Bb = B0; brow = col0; }
  else if (col0 < nb2) { Bb = B1; brow = col0 - nb1; }
  else { Bb = B2; brow = col0 - nb2; }
  const float* bS = Bb + (brow + w * 32 + lr) * (size_t)K + swz * 8 + k0base;

  f32x4 acc[2][4] = {};
  f32x4 blA[4][2], blB[4][2];

#define ALOAD(bufi, kk0)                                                       \
  {                                                                            \
    _Pragma("unroll") for (int i = 0; i < 2; i++)                              \
        GLL(aS + (size_t)(i * 8) * K + (kk0), &As[bufi][(w * 16 + i * 8) * 64]); \
  }
#define BLOAD(blv, kk0)                                                        \
  {                                                                            \
    _Pragma("unroll") for (int i = 0; i < 4; i++) {                            \
      blv[i][0] = *(const f32x4*)(bS + (size_t)(i * 8) * K + (kk0));           \
      blv[i][1] = *(const f32x4*)(bS + (size_t)(i * 8) * K + (kk0) + 4);       \
    }                                                                          \
  }
#define BWRITE(blv, bufi)                                                      \
  {                                                                            \
    _Pragma("unroll") for (int i = 0; i < 4; i++) {                            \
      uint4 pw;                                                                \
      pw.x = pk2(blv[i][0][0], blv[i][0][1]);                                  \
      pw.y = pk2(blv[i][0][2], blv[i][0][3]);                                  \
      pw.z = pk2(blv[i][1][0], blv[i][1][1]);                                  \
      pw.w = pk2(blv[i][1][2], blv[i][1][3]);                                  \
      *(uint4*)&Bs[bufi][(w * 32 + i * 8 + lr) * 64 + lc * 8] = pw;            \
    }                                                                          \
  }

  const int niter = (K >> 1) >> 6;  // 16

  ALOAD(0, 0);
  BLOAD(blA, 0);
  BWRITE(blA, 0);
  BLOAD(blB, 64);
  asm volatile("s_waitcnt lgkmcnt(0)" ::: "memory");
  __builtin_amdgcn_s_barrier();

#define GBODY(it_, blPrev, blCur)                                              \
  {                                                                            \
    const int buf = (it_) & 1;                                                 \
    if ((it_) > 0) {                                                           \
      if ((it_) + 1 < niter) {                                                 \
        asm volatile("s_waitcnt vmcnt(8)" ::: "memory");                       \
      } else {                                                                 \
        asm volatile("s_waitcnt vmcnt(0)" ::: "memory");                       \
      }                                                                        \
      asm volatile("s_waitcnt lgkmcnt(0)" ::: "memory");                       \
      __builtin_amdgcn_s_barrier();                                            \
    }                                                                          \
    if ((it_) + 1 < niter) ALOAD(buf ^ 1, ((it_) + 1) * 64);                   \
    if ((it_) + 2 < niter) BLOAD(blCur, ((it_) + 2) * 64);                     \
    bf16x8 av[2][2], bv[4][2];                                                 \
    _Pragma("unroll") for (int m = 0; m < 2; m++) {                            \
      const int row = wr + m * 16 + cc;                                        \
      _Pragma("unroll") for (int kk = 0; kk < 2; kk++)                         \
          av[m][kk] =                                                          \
              *(const bf16x8*)(&As[buf][row * 64 + (((kk * 4 + g) ^ (cc & 7)) * 8)]); \
    }                                                                          \
    _Pragma("unroll") for (int n = 0; n < 4; n++) {                            \
      const int row = wc + n * 16 + cc;                                        \
      _Pragma("unroll") for (int kk = 0; kk < 2; kk++)                         \
          bv[n][kk] =                                                          \
              *(const bf16x8*)(&Bs[buf][row * 64 + (((kk * 4 + g) ^ (cc & 7)) * 8)]); \
    }                                                                          \
    _Pragma("unroll") for (int kk = 0; kk < 2; kk++)                           \
        _Pragma("unroll") for (int m = 0; m < 2; m++)                          \
        _Pragma("unroll") for (int n = 0; n < 4; n++)                          \
            acc[m][n] = MFMA16(av[m][kk], bv[n][kk], acc[m][n]);               \
    if ((it_) + 1 < niter) BWRITE(blPrev, buf ^ 1);                            \
  }

  for (int it = 0; it < niter; it += 2) {
    GBODY(it, blB, blA);
    GBODY(it + 1, blA, blB);
  }
#undef GBODY
#undef ALOAD
#undef BLOAD
#undef BWRITE

  float* Cw = Cp + (size_t)ks * M * N;
#pragma unroll
  for (int m = 0; m < 2; m++)
#pragma unroll
    for (int n = 0; n < 4; n++)
#pragma unroll
      for (int r = 0; r < 4; r++)
        Cw[(row0 + wr + m * 16 + g * 4 + r) * N + (col0 + wc + n * 16 + cc)] = acc[m][n][r];
}

// ---------------- RoPE + scatter (reads K-split partial sums) ----------------
__global__ __launch_bounds__(256) void postproc(const float* __restrict__ Cp0,
                                                const float* __restrict__ Cp1,
                                                const float* __restrict__ fcos,
                                                const float* __restrict__ fsin,
                                                u16* __restrict__ qrope,
                                                u16* __restrict__ kfull,
                                                float* __restrict__ newk,
                                                float* __restrict__ newv) {
  int idx = blockIdx.x * 256 + threadIdx.x;
  if (idx >= 1024 * 1536) return;
  int m = idx / 1536, p = idx - m * 1536;
  int b = m >> 9, s = m & 511;
  const float* r0 = Cp0 + (size_t)m * 3072;
  const float* r1 = Cp1 + (size_t)m * 3072;
  if (p < 1280) {
    bool isq = p < 1024;
    int pk = isq ? p : p - 1024;
    int h = pk >> 5, i = pk & 31;
    int colbase = (isq ? 0 : 2048) + h * 64 + 2 * i;
    float xr = r0[colbase] + r1[colbase];
    float xi = r0[colbase + 1] + r1[colbase + 1];
    float co = fcos[s * 32 + i], si = fsin[s * 32 + i];
    float orr = xr * co - xi * si;
    float oii = xr * si + xi * co;
    if (isq) {
      u16* dst = qrope + (((size_t)(b * 32 + h) * 512 + s) * 64 + 2 * i);
      dst[0] = f2b(orr); dst[1] = f2b(oii);
    } else {
      size_t o0 = ((size_t)(b * 8 + h) * 512 + s) * 64 + 2 * i;
      newk[o0] = orr; newk[o0 + 1] = oii;
      u16* kf = kfull + (((size_t)(b * 8 + h) * 2048 + 1536 + s) * 64 + 2 * i);
      kf[0] = f2b(orr); kf[1] = f2b(oii);
    }
  } else {
    int pv = p - 1280;
    int h = pv >> 5, i = pv & 31;
    int cb = 2560 + h * 64 + 2 * i;
    float v0 = r0[cb] + r1[cb], v1 = r0[cb + 1] + r1[cb + 1];
    size_t o0 = ((size_t)(b * 8 + h) * 512 + s) * 64 + 2 * i;
    newv[o0] = v0; newv[o0 + 1] = v1;
  }
}

// sum K-split partials -> out (f32)
__global__ __launch_bounds__(256) void sumout(const float* __restrict__ a,
                                              const float* __restrict__ b,
                                              float* __restrict__ out) {
  const int i = blockIdx.x * 256 + threadIdx.x;  // 524288 float4 chunks
  const float4 va = *(const float4*)(a + (size_t)i * 4);
  const float4 vb = *(const float4*)(b + (size_t)i * 4);
  float4 o;
  o.x = va.x + vb.x; o.y = va.y + vb.y; o.z = va.z + vb.z; o.w = va.w + vb.w;
  *(float4*)(out + (size_t)i * 4) = o;
}

// ---------------- flash attention: 8-wave blocks, KV-split 2-way ----------------
// 4-deep LDS pipeline, raw s_barrier + counted vmcnt (T3/T4), setprio on MFMA (T5).
// Packed-b64 P writes (kv-slot permutation matching vT2).
__global__ __launch_bounds__(512, 4) void attn_split(const u16* __restrict__ qrope,
                                                     const u16* __restrict__ kfull,
                                                     const u16* __restrict__ vT,
                                                     const float* __restrict__ mask,
                                                     float* __restrict__ po,
                                                     float* __restrict__ ml) {
  __shared__ __attribute__((aligned(16))) u16 Ks[4][4096];  // [buf][64 kv][64 d] 32KB
  __shared__ __attribute__((aligned(16))) u16 Vs[4][4096];  // [buf][64 d][64 kv] 32KB
  __shared__ __attribute__((aligned(16))) u16 P_lds[8192];  // 8 waves x 16x64   16KB
  const int t = threadIdx.x, lane = t & 63, w = t >> 6;  // w in 0..7
  const int g = lane >> 4, cc = lane & 15;
  const int p = blockIdx.x;
  const int v = (p & 7) * 64 + (p >> 3);
  const int bh = v >> 3, qt = (v >> 1) & 3, sp = v & 1;
  const int b = bh >> 5, h = bh & 31;
  const int bhkv = b * 8 + (h >> 2);
  const int s0 = qt * 128 + w * 16;
  const int j0beg = sp * 1024;

  const int lr = lane >> 3, lc = lane & 7;
  const int swzc = lc ^ lr;

  bf16x8 qa0, qa1;
  {
    const u16* qb = qrope + ((size_t)bh * 512 + s0 + cc) * 64 + g * 8;
    qa0 = *(const bf16x8*)qb;
    qa1 = *(const bf16x8*)(qb + 32);
  }
  float mrow[4], lsum[4];
  f32x4 o[4] = {};
#pragma unroll
  for (int r = 0; r < 4; r++) { mrow[r] = -1e30f; lsum[r] = 0.0f; }

  u16* Pw = P_lds + w * 1024;
  const float* mbase = mask + (size_t)(s0 + g * 4) * 2048 + cc;
  const u16* ksrc0 = kfull + (size_t)bhkv * 131072 + (size_t)(w * 8 + lr) * 64 + swzc * 8;
  const u16* vsrc0 = vT + ((size_t)bhkv * 64 + w * 8 + lr) * 2048 + swzc * 8;

#pragma unroll
  for (int pt = 0; pt < 3; ++pt) {
    GLL(ksrc0 + (size_t)(j0beg + pt * 64) * 64, &Ks[pt][w * 512]);
    GLL(vsrc0 + (j0beg + pt * 64), &Vs[pt][w * 512]);
  }

  for (int it = 0; it < 16; ++it) {
    const int buf = it & 3;
    const int j0 = j0beg + it * 64;
    if (it < 14) {
      asm volatile("s_waitcnt vmcnt(4)" ::: "memory");
    } else if (it == 14) {
      asm volatile("s_waitcnt vmcnt(2)" ::: "memory");
    } else {
      asm volatile("s_waitcnt vmcnt(0)" ::: "memory");
    }
    __builtin_amdgcn_s_barrier();

    float mk[4][4];
#pragma unroll
    for (int r = 0; r < 4; r++)
#pragma unroll
      for (int jb = 0; jb < 4; jb++)
        mk[r][jb] = mbase[(size_t)r * 2048 + j0 + jb * 16];
    __builtin_amdgcn_sched_barrier(0);
    if (it < 13) {
      GLL(ksrc0 + (size_t)(j0 + 192) * 64, &Ks[(it + 3) & 3][w * 512]);
      GLL(vsrc0 + (j0 + 192), &Vs[(it + 3) & 3][w * 512]);
    }

    f32x4 sc[4];
    __builtin_amdgcn_s_setprio(1);
#pragma unroll
    for (int jb = 0; jb < 4; jb++) {
      const bf16x8 k0 = *(const bf16x8*)(&Ks[buf][(jb * 16 + cc) * 64 + ((g ^ (cc & 7)) * 8)]);
      const bf16x8 k1 =
          *(const bf16x8*)(&Ks[buf][(jb * 16 + cc) * 64 + (((g + 4) ^ (cc & 7)) * 8)]);
      f32x4 z = {0.f, 0.f, 0.f, 0.f};
      z = MFMA16(qa0, k0, z);
      z = MFMA16(qa1, k1, z);
      sc[jb] = z;
    }
    __builtin_amdgcn_s_setprio(0);
    float pp[4][4];
#pragma unroll
    for (int r = 0; r < 4; r++) {
#pragma unroll
      for (int jb = 0; jb < 4; jb++)
        pp[r][jb] = sc[jb][r] * 0.125f + mk[r][jb];
      const float lm = fmaxf(fmaxf(pp[r][0], pp[r][1]), fmaxf(pp[r][2], pp[r][3]));
      if (__any(lm > mrow[r] + 8.0f)) {
        float tm = lm;
#pragma unroll
        for (int off = 1; off < 16; off <<= 1) tm = fmaxf(tm, __shfl_xor(tm, off, 64));
        const float newm = fmaxf(mrow[r], tm);
        const float corr = __expf(mrow[r] - newm);
        mrow[r] = newm;
        lsum[r] *= corr;
#pragma unroll
        for (int db = 0; db < 4; db++) o[db][r] *= corr;
      }
      float ps = 0.f;
#pragma unroll
      for (int jb = 0; jb < 4; jb++) { pp[r][jb] = __expf(pp[r][jb] - mrow[r]); ps += pp[r][jb]; }
      lsum[r] += ps;
      // packed P write: value(kv=jb*16+cc) -> slot cc*4+jb; bytes cc*8+jb*2, XOR sw
      const int rowb = (g * 4 + r) * 128;
      const int sw = ((g * 4 + r) & 7) << 4;
      uint2 pw;
      pw.x = pk2(pp[r][0], pp[r][1]);
      pw.y = pk2(pp[r][2], pp[r][3]);
      *(uint2*)((char*)Pw + ((rowb + cc * 8) ^ sw)) = pw;
    }
    __builtin_amdgcn_s_setprio(1);
#pragma unroll
    for (int kk = 0; kk < 2; kk++) {
      const bf16x8 pa =
          *(const bf16x8*)(Pw + (((cc * 128 + kk * 64 + g * 16) ^ ((cc & 7) << 4)) >> 1));
#pragma unroll
      for (int db = 0; db < 4; db++) {
        const bf16x8 vf =
            *(const bf16x8*)(&Vs[buf][(db * 16 + cc) * 64 + (((kk * 4 + g) ^ (cc & 7)) * 8)]);
        o[db] = MFMA16(pa, vf, o[db]);
      }
    }
    __builtin_amdgcn_s_setprio(0);
  }
#pragma unroll
  for (int r = 0; r < 4; r++) {
    float ps = lsum[r];
#pragma unroll
    for (int off = 1; off < 16; off <<= 1) ps += __shfl_xor(ps, off, 64);
    const size_t row = (size_t)bh * 512 + s0 + g * 4 + r;
    float* dst = po + (row * 2 + sp) * 64 + cc;
#pragma unroll
    for (int db = 0; db < 4; db++) dst[db * 16] = o[db][r];
    if (cc == 0) {
      float2* mlp = (float2*)ml;
      mlp[row * 2 + sp] = make_float2(mrow[r], ps);
    }
  }
}

// combine 2 splits -> aout bf16 [1024][2048] (b,s, h*64+d)
__global__ __launch_bounds__(256) void attn_combine(const float* __restrict__ po,
                                                    const float* __restrict__ ml,
                                                    u16* __restrict__ aout) {
  const int t = threadIdx.x;
  const int row = blockIdx.x * 4 + (t >> 6);  // bh*512 + s
  const int d = t & 63;
  const int bh = row >> 9, s = row & 511;
  const int b = bh >> 5, h = bh & 31;
  const float2* mlp = (const float2*)ml;
  const float2 m0 = mlp[row * 2 + 0], m1 = mlp[row * 2 + 1];
  const float M = fmaxf(m0.x, m1.x);
  const float w0 = __expf(m0.x - M), w1 = __expf(m1.x - M);
  const float L = m0.y * w0 + m1.y * w1;
  const float o = po[(size_t)(row * 2 + 0) * 64 + d] * w0 +
                  po[(size_t)(row * 2 + 1) * 64 + d] * w1;
  aout[((size_t)(b * 512 + s)) * 2048 + h * 64 + d] = f2b(o / L);
}

// ---------------- launch ----------------
extern "C" void kernel_launch(void* const* d_in, const int* in_sizes, int n_in,
                              void* d_out, int out_size, void* d_ws, size_t ws_size,
                              hipStream_t stream) {
  (void)in_sizes; (void)n_in; (void)out_size; (void)ws_size;
  const float* x    = (const float*)d_in[0];
  const float* fcos = (const float*)d_in[1];
  const float* fsin = (const float*)d_in[2];
  const float* kc   = (const float*)d_in[3];
  const float* vc   = (const float*)d_in[4];
  const float* mask = (const float*)d_in[5];
  const float* wq   = (const float*)d_in[6];
  const float* wk   = (const float*)d_in[7];
  const float* wv   = (const float*)d_in[8];
  const float* wo   = (const float*)d_in[9];

  float* out_f = (float*)d_out;                 // [2][512][2048]
  float* newk  = out_f + 2097152;               // [2][8][512][64]
  float* newv  = out_f + 2621440;               // [2][8][512][64]

  u16*   xb    = (u16*)d_ws;                    // 4MB   @0    (dead after gemm1)
  float* Cp    = (float*)(xb + 2097152);        // 24MB  @4MB  (2 partials; dead after postproc)
  float* Cp1   = Cp + 3145728;
  u16*   qrope = (u16*)(Cp + 6291456);          // 4MB   @28MB
  u16*   kfull = qrope + 2097152;               // 4MB   @32MB
  u16*   vTf   = kfull + 2097152;               // 4MB   @36MB
  u16*   aout  = vTf + 2097152;                 // 4MB   @40MB
  float* ml    = (float*)(aout + 2097152);      // 0.5MB @44MB
  // phase aliases:
  float* po    = (float*)d_ws;                  // 16MB @0 (over xb+Cp0; both dead by attn)
  float* Co    = (float*)d_ws;                  // 16MB @0 (over po; dead after combine)
  float* Co1   = Co + 2097152;

  prep<<<3968, 256, 0, stream>>>(x, kc, vc, xb, kfull, vTf);

  gemm_bt<<<768, 256, 0, stream>>>(xb, wq, wk, wv, Cp,
                                   1024, 3072, 2048, 2048, 2560);
  postproc<<<6144, 256, 0, stream>>>(Cp, Cp1, fcos, fsin, qrope, kfull, newk, newv);
  vtrn<<<dim3(8, 16), 256, 0, stream>>>(newv, vTf);
  attn_split<<<512, 512, 0, stream>>>(qrope, kfull, vTf, mask, po, ml);
  attn_combine<<<8192, 256, 0, stream>>>(po, ml, aout);
  gemm_bt<<<512, 256, 0, stream>>>(aout, wo, wo, wo, Co,
                                   1024, 2048, 2048, 4096, 8192);
  sumout<<<2048, 256, 0, stream>>>(Co, Co1, out_f);
}